// Round 1
// baseline (299.929 us; speedup 1.0000x reference)
//
#include <hip/hip_runtime.h>
#include <math.h>

#define BB 8
#define CC 256
#define HH 256
#define WW 256
#define HWC (HH * WW)            // 65536 = 2^16
#define BHW (BB * HWC)           // 524288
#define CHW (CC * HWC)           // 16777216 = 2^24

// ---------------------------------------------------------------------------
// K1: channel-wise mean and max. One thread per float4 group of (b, h, w).
// Reads 512 MiB coalesced, writes 4 MiB of avg/max planes.
// ---------------------------------------------------------------------------
__global__ __launch_bounds__(256) void k_stats(const float* __restrict__ x,
                                               float* __restrict__ avgp,
                                               float* __restrict__ maxp) {
    int g = blockIdx.x * 256 + threadIdx.x;       // float4 group over BHW/4
    if (g >= BHW / 4) return;
    int e   = g << 2;                             // flat pixel index (b*HW + pix)
    int b   = e >> 16;
    int pix = e & (HWC - 1);

    const float4* x4 = (const float4*)x + (((size_t)b * CHW + pix) >> 2);
    const int cstride = HWC >> 2;                 // float4s per channel plane

    float4 v = x4[0];
    float4 s = v;
    float4 m = v;
#pragma unroll 4
    for (int c = 1; c < CC; ++c) {
        float4 t = x4[(size_t)c * cstride];
        s.x += t.x; s.y += t.y; s.z += t.z; s.w += t.w;
        m.x = fmaxf(m.x, t.x); m.y = fmaxf(m.y, t.y);
        m.z = fmaxf(m.z, t.z); m.w = fmaxf(m.w, t.w);
    }
    const float inv = 1.0f / (float)CC;
    float4 a = { s.x * inv, s.y * inv, s.z * inv, s.w * inv };
    ((float4*)avgp)[g] = a;
    ((float4*)maxp)[g] = m;
}

// ---------------------------------------------------------------------------
// K2: 7x7 conv (2->1 ch, SAME zero pad) + bias + sigmoid over the 4 MiB
// stats planes. One thread per pixel. L2-resident; negligible time.
// ---------------------------------------------------------------------------
__global__ __launch_bounds__(256) void k_conv(const float* __restrict__ avgp,
                                              const float* __restrict__ maxp,
                                              const float* __restrict__ cw,
                                              const float* __restrict__ cb,
                                              float* __restrict__ attnp) {
    int t = blockIdx.x * 256 + threadIdx.x;       // pixel over BHW
    if (t >= BHW) return;
    int b   = t >> 16;
    int pix = t & (HWC - 1);
    int h   = pix >> 8;
    int w   = pix & (WW - 1);

    const float* ap = avgp + (size_t)b * HWC;
    const float* mp = maxp + (size_t)b * HWC;

    float sum = cb[0];
#pragma unroll
    for (int kh = 0; kh < 7; ++kh) {
        int hh = h + kh - 3;
        if ((unsigned)hh >= (unsigned)HH) continue;
#pragma unroll
        for (int kw = 0; kw < 7; ++kw) {
            int ww = w + kw - 3;
            if ((unsigned)ww >= (unsigned)WW) continue;
            int o = (hh << 8) + ww;
            float wa = cw[kh * 7 + kw];
            float wm = cw[49 + kh * 7 + kw];
            sum = fmaf(wa, ap[o], sum);
            sum = fmaf(wm, mp[o], sum);
        }
    }
    // sigmoid
    attnp[t] = 1.0f / (1.0f + __expf(-sum));
}

// ---------------------------------------------------------------------------
// K3: out = x * attn (attn broadcast over channels). Pure streaming float4.
// ---------------------------------------------------------------------------
__global__ __launch_bounds__(256) void k_mul(const float* __restrict__ x,
                                             const float* __restrict__ attnp,
                                             float* __restrict__ out) {
    size_t g = (size_t)blockIdx.x * 256 + threadIdx.x;  // float4 idx over BCHW/4
    size_t e = g << 2;                                  // flat element index
    size_t b   = e >> 24;                               // / CHW
    size_t pix = e & (size_t)(HWC - 1);                 // % HW

    float4 a = *((const float4*)attnp + (((b << 16) + pix) >> 2));
    float4 v = ((const float4*)x)[g];
    float4 o = { v.x * a.x, v.y * a.y, v.z * a.z, v.w * a.w };
    ((float4*)out)[g] = o;
}

extern "C" void kernel_launch(void* const* d_in, const int* in_sizes, int n_in,
                              void* d_out, int out_size, void* d_ws, size_t ws_size,
                              hipStream_t stream) {
    const float* x  = (const float*)d_in[0];
    const float* cw = (const float*)d_in[1];   // (1,2,7,7) = 98 floats
    const float* cb = (const float*)d_in[2];   // 1 float
    float* out = (float*)d_out;

    // workspace layout: avg plane | max plane | attn plane  (BHW floats each)
    float* avgp  = (float*)d_ws;
    float* maxp  = avgp + BHW;
    float* attnp = maxp + BHW;

    // K1: BHW/4 threads
    {
        int nthreads = BHW / 4;                 // 131072
        int nblocks  = (nthreads + 255) / 256;  // 512
        k_stats<<<nblocks, 256, 0, stream>>>(x, avgp, maxp);
    }
    // K2: BHW threads
    {
        int nblocks = (BHW + 255) / 256;        // 2048
        k_conv<<<nblocks, 256, 0, stream>>>(avgp, maxp, cw, cb, attnp);
    }
    // K3: BCHW/4 threads
    {
        long long total = (long long)BB * CHW / 4;  // 33554432
        int nblocks = (int)((total + 255) / 256);   // 131072
        k_mul<<<nblocks, 256, 0, stream>>>(x, attnp, out);
    }
}